// Round 5
// baseline (2090.331 us; speedup 1.0000x reference)
//
#include <hip/hip_runtime.h>

typedef __bf16 bf16_t;
typedef __bf16 bf16x8 __attribute__((ext_vector_type(8)));
typedef float  f32x4  __attribute__((ext_vector_type(4)));

#define MFMA16(a, b, c) __builtin_amdgcn_mfma_f32_16x16x32_bf16((a), (b), (c), 0, 0, 0)
#define LOG2E 1.44269504f

// 8-element loaders -> bf16x8 (fp32 source converts on the fly)
__device__ inline bf16x8 load8(const bf16_t* p) { return *(const bf16x8*)p; }
__device__ inline bf16x8 load8(const float* p) {
    f32x4 a = *(const f32x4*)p;
    f32x4 b = *(const f32x4*)(p + 4);
    bf16x8 r;
    r[0] = (bf16_t)a[0]; r[1] = (bf16_t)a[1]; r[2] = (bf16_t)a[2]; r[3] = (bf16_t)a[3];
    r[4] = (bf16_t)b[0]; r[5] = (bf16_t)b[1]; r[6] = (bf16_t)b[2]; r[7] = (bf16_t)b[3];
    return r;
}

// ---------------------------------------------------------------------------
// proj_gemm: C[m,n] = X[m,:] . W[n,:] + bias[n]   (X @ W^T + b)
// M = 8192, N = 768, K = 768. 64x64 tile / block, 4 waves, 16x64 slab each.
// XT = input dtype (fp32 raw inputs / bf16 attention out); OT = output dtype.
// mode 0: write (B,H,S,64) head-major (OT=bf16); mode 1: flat [m*768+n]
// (OT=float -> final fp32 output of the whole op).
// ---------------------------------------------------------------------------
template <typename XT, typename OT>
__global__ void __launch_bounds__(256)
proj_gemm(const XT* __restrict__ X, const float* __restrict__ W,
          const float* __restrict__ bias, OT* __restrict__ Out, int mode)
{
    __shared__ bf16_t Al[64][72];
    __shared__ bf16_t Bl[64][72];

    const int tid  = threadIdx.x;
    const int m0   = blockIdx.x * 64;
    const int n0   = blockIdx.y * 64;
    const int w    = tid >> 6;
    const int lane = tid & 63;
    const int quad = lane >> 4;
    const int l16  = lane & 15;

    f32x4 acc[4];
#pragma unroll
    for (int nt = 0; nt < 4; ++nt)
#pragma unroll
        for (int r = 0; r < 4; ++r) acc[nt][r] = 0.0f;

    for (int kc = 0; kc < 12; ++kc) {
        const int k0 = kc * 64;
        __syncthreads();
#pragma unroll
        for (int p = 0; p < 2; ++p) {
            const int row = p * 32 + (tid >> 3);
            const int col = (tid & 7) * 8;
            *(bf16x8*)&Al[row][col] = load8(X + (size_t)(m0 + row) * 768 + k0 + col);
            *(bf16x8*)&Bl[row][col] = load8(W + (size_t)(n0 + row) * 768 + k0 + col);
        }
        __syncthreads();
#pragma unroll
        for (int kk = 0; kk < 2; ++kk) {
            bf16x8 a = *(const bf16x8*)&Al[16 * w + l16][kk * 32 + quad * 8];
#pragma unroll
            for (int nt = 0; nt < 4; ++nt) {
                bf16x8 b = *(const bf16x8*)&Bl[16 * nt + l16][kk * 32 + quad * 8];
                acc[nt] = MFMA16(a, b, acc[nt]);
            }
        }
    }

#pragma unroll
    for (int nt = 0; nt < 4; ++nt) {
        const int n  = n0 + nt * 16 + l16;
        const float bn = bias[n];
#pragma unroll
        for (int r = 0; r < 4; ++r) {
            const int m = m0 + 16 * w + quad * 4 + r;
            const float v = acc[nt][r] + bn;
            if (mode == 0) {
                const int bb = m >> 10, ss = m & 1023, hh = n >> 6, dd = n & 63;
                Out[(((size_t)(bb * 12 + hh)) * 1024 + ss) * 64 + dd] = (OT)v;
            } else {
                Out[(size_t)m * 768 + n] = (OT)v;
            }
        }
    }
}

// ---------------------------------------------------------------------------
// naive_attn: DIAGNOSTIC correct-first attention (unchanged from round 4).
// Block = (b,h, 64 q-rows); 4 waves x 16 rows sequential per wave.
// Per t-tile: stage K/V (fp32 LDS), Er strip (bf16 LDS); per row:
//   lane=t: logit_t = sum_d q[s,d]*(K[t,d] + Er[1023-s+t, d]) / 8, causal mask
//   full-wave butterfly softmax (online, running m/l)
//   lane=d: out_d = out_d*alpha + sum_t P_t * V[t,d]
// ---------------------------------------------------------------------------
__global__ void __launch_bounds__(256)
naive_attn(const bf16_t* __restrict__ qb, const bf16_t* __restrict__ kb,
           const bf16_t* __restrict__ vb, const float* __restrict__ Er,
           bf16_t* __restrict__ att)
{
    __shared__ float  Ql[64][65];
    __shared__ float  Kl[64][65];
    __shared__ float  Vl[64][65];
    __shared__ bf16_t Erl[128][66];
    __shared__ float  Pbuf[4][64];

    const int tid  = threadIdx.x;
    const int bid  = blockIdx.x;
    const int qt   = 15 - (bid & 15);    // heavy q-tiles dispatched first
    const int bh   = bid >> 4;
    const int b    = bh / 12;
    const int h    = bh % 12;
    const int s0   = qt * 64;
    const int w    = tid >> 6;
    const int lane = tid & 63;

    const bf16_t* qp = qb + (size_t)bh * 65536;
    const bf16_t* kp = kb + (size_t)bh * 65536;
    const bf16_t* vp = vb + (size_t)bh * 65536;

    // stage Q once (fp32 LDS)
    {
        const int row = tid >> 2;
        const int c0  = (tid & 3) * 16;
#pragma unroll
        for (int jj = 0; jj < 16; ++jj)
            Ql[row][c0 + jj] = (float)qp[(size_t)(s0 + row) * 64 + c0 + jj];
    }

    float mrun[16], lrun[16], out[16];
#pragma unroll
    for (int i = 0; i < 16; ++i) { mrun[i] = -1e30f; lrun[i] = 0.f; out[i] = 0.f; }

    const int nT = qt + 1;
    for (int tt = 0; tt < nT; ++tt) {
        const int t0 = tt * 64;
        const int E0 = 960 - s0 + t0;     // Erl[r] = Er[E0 + r]; needed r = 63 - sl + lane

        __syncthreads();
        {
            const int row = tid >> 2;
            const int c0  = (tid & 3) * 16;
#pragma unroll
            for (int jj = 0; jj < 16; ++jj) {
                Kl[row][c0 + jj] = (float)kp[(size_t)(t0 + row) * 64 + c0 + jj];
                Vl[row][c0 + jj] = (float)vp[(size_t)(t0 + row) * 64 + c0 + jj];
            }
        }
        {
            const int row = tid >> 1;         // 0..127
            const int c0  = (tid & 1) * 32;   // 0,32
            const int e   = E0 + row;
            if (e < 1024) {
#pragma unroll
                for (int jj = 0; jj < 32; ++jj)
                    Erl[row][c0 + jj] = (bf16_t)Er[(size_t)e * 64 + c0 + jj];
            } else {
#pragma unroll
                for (int jj = 0; jj < 32; ++jj)
                    Erl[row][c0 + jj] = (bf16_t)0.f;
            }
        }
        __syncthreads();

#pragma unroll 1
        for (int i = 0; i < 16; ++i) {
            const int sl = 16 * w + i;
            const int s  = s0 + sl;

            // phase 1: lane = t_local
            float lg = 0.f;
            const int er_row = 63 - sl + lane;   // in [0,127]
#pragma unroll 8
            for (int d = 0; d < 64; ++d)
                lg += Ql[sl][d] * (Kl[lane][d] + (float)Erl[er_row][d]);
            lg *= 0.125f;
            if (t0 + lane > s) lg = -1e30f;

            // online softmax, full 64-lane butterfly
            float vm = lg;
#pragma unroll
            for (int off = 1; off < 64; off <<= 1)
                vm = fmaxf(vm, __shfl_xor(vm, off));
            const float mnew  = fmaxf(mrun[i], vm);
            const float alpha = __builtin_exp2f((mrun[i] - mnew) * LOG2E);
            const float p     = __builtin_exp2f((lg - mnew) * LOG2E);
            float rs = p;
#pragma unroll
            for (int off = 1; off < 64; off <<= 1)
                rs += __shfl_xor(rs, off);
            lrun[i] = lrun[i] * alpha + rs;
            mrun[i] = mnew;
            Pbuf[w][lane] = p;   // intra-wave LDS: DS pipe processes a wave's ops in order

            // phase 2: lane = d
            float acc = 0.f;
#pragma unroll 8
            for (int j = 0; j < 64; ++j)
                acc += Pbuf[w][j] * Vl[j][lane];
            out[i] = out[i] * alpha + acc;
        }
    }

#pragma unroll
    for (int i = 0; i < 16; ++i) {
        const int s = s0 + 16 * w + i;
        att[((size_t)b * 1024 + s) * 768 + h * 64 + lane] = (bf16_t)(out[i] / lrun[i]);
    }
}

// ---------------------------------------------------------------------------
extern "C" void kernel_launch(void* const* d_in, const int* in_sizes, int n_in,
                              void* d_out, int out_size, void* d_ws, size_t ws_size,
                              hipStream_t stream)
{
    const float* Q  = (const float*)d_in[0];
    const float* K  = (const float*)d_in[1];
    const float* V  = (const float*)d_in[2];
    // d_in[3] = causal mask — semantics reproduced in-kernel (fp32, verified r1 NaN probe)
    const float* Wq = (const float*)d_in[4];
    const float* bq = (const float*)d_in[5];
    const float* Wk = (const float*)d_in[6];
    const float* bk = (const float*)d_in[7];
    const float* Wv = (const float*)d_in[8];
    const float* bv = (const float*)d_in[9];
    const float* Wo = (const float*)d_in[10];
    const float* bo = (const float*)d_in[11];
    const float* Er = (const float*)d_in[12];
    float* out      = (float*)d_out;     // OUTPUT IS FP32 (reference output dtype)

    const size_t per = (size_t)8 * 12 * 1024 * 64;   // 6.29M elems per head-tensor
    // q (bf16, 12.6MB) borrows d_out's front half (25.2MB fp32); q is dead
    // before the final fp32 epilogue overwrites the buffer.
    bf16_t* qbuf = (bf16_t*)d_out;
    bf16_t* kbuf = (bf16_t*)d_ws;
    bf16_t* vbuf = kbuf + per;
    bf16_t* abuf = vbuf + per;           // (B,S,768) attention out, bf16

    dim3 gp(128, 12), bp(256);
    proj_gemm<float, bf16_t><<<gp, bp, 0, stream>>>(Q, Wq, bq, qbuf, 0);
    proj_gemm<float, bf16_t><<<gp, bp, 0, stream>>>(K, Wk, bk, kbuf, 0);
    proj_gemm<float, bf16_t><<<gp, bp, 0, stream>>>(V, Wv, bv, vbuf, 0);
    naive_attn<<<dim3(8 * 12 * 16), bp, 0, stream>>>(qbuf, kbuf, vbuf, Er, abuf);
    proj_gemm<bf16_t, float><<<gp, bp, 0, stream>>>(abuf, Wo, bo, out, 1);
}

// Round 6
// 459.671 us; speedup vs baseline: 4.5475x; 4.5475x over previous
//
#include <hip/hip_runtime.h>

typedef __bf16 bf16_t;
typedef __bf16 bf16x8 __attribute__((ext_vector_type(8)));
typedef float  f32x4  __attribute__((ext_vector_type(4)));

#define MFMA16(a, b, c) __builtin_amdgcn_mfma_f32_16x16x32_bf16((a), (b), (c), 0, 0, 0)
#define LOG2E 1.44269504f

// 8-element loaders -> bf16x8 (fp32 source converts on the fly)
__device__ inline bf16x8 load8(const bf16_t* p) { return *(const bf16x8*)p; }
__device__ inline bf16x8 load8(const float* p) {
    f32x4 a = *(const f32x4*)p;
    f32x4 b = *(const f32x4*)(p + 4);
    bf16x8 r;
    r[0] = (bf16_t)a[0]; r[1] = (bf16_t)a[1]; r[2] = (bf16_t)a[2]; r[3] = (bf16_t)a[3];
    r[4] = (bf16_t)b[0]; r[5] = (bf16_t)b[1]; r[6] = (bf16_t)b[2]; r[7] = (bf16_t)b[3];
    return r;
}

// ---------------------------------------------------------------------------
// proj_gemm: C[m,n] = X[m,:] . W[n,:] + bias[n]   (X @ W^T + b)
// M = 8192, N = 768, K = 768. 64x64 tile / block, 4 waves, 16x64 slab each.
// XT = input dtype; OT = output dtype.
// mode 0: write (B,H,S,64) head-major (OT=bf16); mode 1: flat [m*768+n]
// (OT=float -> final fp32 output of the whole op).
// ---------------------------------------------------------------------------
template <typename XT, typename OT>
__global__ void __launch_bounds__(256)
proj_gemm(const XT* __restrict__ X, const float* __restrict__ W,
          const float* __restrict__ bias, OT* __restrict__ Out, int mode)
{
    __shared__ bf16_t Al[64][72];
    __shared__ bf16_t Bl[64][72];

    const int tid  = threadIdx.x;
    const int m0   = blockIdx.x * 64;
    const int n0   = blockIdx.y * 64;
    const int w    = tid >> 6;
    const int lane = tid & 63;
    const int quad = lane >> 4;
    const int l16  = lane & 15;

    f32x4 acc[4];
#pragma unroll
    for (int nt = 0; nt < 4; ++nt)
#pragma unroll
        for (int r = 0; r < 4; ++r) acc[nt][r] = 0.0f;

    for (int kc = 0; kc < 12; ++kc) {
        const int k0 = kc * 64;
        __syncthreads();
#pragma unroll
        for (int p = 0; p < 2; ++p) {
            const int row = p * 32 + (tid >> 3);
            const int col = (tid & 7) * 8;
            *(bf16x8*)&Al[row][col] = load8(X + (size_t)(m0 + row) * 768 + k0 + col);
            *(bf16x8*)&Bl[row][col] = load8(W + (size_t)(n0 + row) * 768 + k0 + col);
        }
        __syncthreads();
#pragma unroll
        for (int kk = 0; kk < 2; ++kk) {
            bf16x8 a = *(const bf16x8*)&Al[16 * w + l16][kk * 32 + quad * 8];
#pragma unroll
            for (int nt = 0; nt < 4; ++nt) {
                bf16x8 b = *(const bf16x8*)&Bl[16 * nt + l16][kk * 32 + quad * 8];
                acc[nt] = MFMA16(a, b, acc[nt]);
            }
        }
    }

#pragma unroll
    for (int nt = 0; nt < 4; ++nt) {
        const int n  = n0 + nt * 16 + l16;
        const float bn = bias[n];
#pragma unroll
        for (int r = 0; r < 4; ++r) {
            const int m = m0 + 16 * w + quad * 4 + r;
            const float v = acc[nt][r] + bn;
            if (mode == 0) {
                const int bb = m >> 10, ss = m & 1023, hh = n >> 6, dd = n & 63;
                Out[(((size_t)(bb * 12 + hh)) * 1024 + ss) * 64 + dd] = (OT)v;
            } else {
                Out[(size_t)m * 768 + n] = (OT)v;
            }
        }
    }
}

// ---------------------------------------------------------------------------
// attn_kernel: MFMA flash attention with Music-Transformer relative position.
// Block = (b, h, 64 q-rows). 4 waves, each owns 16 q-rows.
// Srel[s,t] = q[s] . Er[1023-s+t]  (only t<=s survives the causal mask).
// Per t-tile: strip GEMM G[i,u] = q . Er[E0+u0_w+u]; Srel[i][j] = G[i][15-i+j]
// (u = 15-i+j, E0 = 960-s0+t0). Verified vs trusted naive_attn algebra (r5).
// ---------------------------------------------------------------------------
__global__ void __launch_bounds__(256)
attn_kernel(const bf16_t* __restrict__ qb, const bf16_t* __restrict__ kb,
            const bf16_t* __restrict__ vb, const float* __restrict__ Er,
            bf16_t* __restrict__ att)
{
    __shared__ bf16_t Kl[64][72];        // K tile, row t_local
    __shared__ bf16_t Vtl[64][72];       // V tile transposed: Vtl[d][t_local]
    __shared__ bf16_t Erl[128][72];      // Er rows E0..E0+127 (zero past S)
    __shared__ bf16_t Pl[4][16][72];     // per-wave P round-trip (wave-private)
    __shared__ bf16_t Gl[4][16][80];     // per-wave G strip     (wave-private)

    const int tid  = threadIdx.x;
    const int bid  = blockIdx.x;
    const int qt   = 15 - (bid & 15);    // heavy q-tiles dispatched first
    const int bh   = bid >> 4;           // 0..95
    const int b    = bh / 12;
    const int h    = bh % 12;
    const int s0   = qt * 64;
    const int w    = tid >> 6;
    const int lane = tid & 63;
    const int quad = lane >> 4;
    const int l16  = lane & 15;
    const int s0w  = s0 + 16 * w;
    const int u0   = 48 - 16 * w;

    const bf16_t* qp = qb + (size_t)bh * 65536;
    const bf16_t* kp = kb + (size_t)bh * 65536;
    const bf16_t* vp = vb + (size_t)bh * 65536;

    // q fragments (A-layout: [m=l16][k=quad*8+j])
    bf16x8 aq[2];
#pragma unroll
    for (int kk = 0; kk < 2; ++kk)
        aq[kk] = *(const bf16x8*)(qp + (size_t)(s0w + l16) * 64 + kk * 32 + quad * 8);

    float mrow[4], lrow[4];
    f32x4 o[4];
#pragma unroll
    for (int r = 0; r < 4; ++r) { mrow[r] = -1e30f; lrow[r] = 0.0f; }
#pragma unroll
    for (int nt = 0; nt < 4; ++nt)
#pragma unroll
        for (int r = 0; r < 4; ++r) o[nt][r] = 0.0f;

    const int nT = qt + 1;
    for (int tt = 0; tt < nT; ++tt) {
        const int t0 = tt * 64;
        const int E0 = 960 - s0 + t0;    // >= 0 always

        __syncthreads();                 // protect Kl/Vtl/Erl re-stage
        // --- stage K, V^T (bf16 src), Er strip (fp32 src -> bf16) ---
#pragma unroll
        for (int p = 0; p < 2; ++p) {
            const int row = p * 32 + (tid >> 3);
            const int col = (tid & 7) * 8;
            *(bf16x8*)&Kl[row][col] = load8(kp + (size_t)(t0 + row) * 64 + col);
            bf16x8 vv = load8(vp + (size_t)(t0 + row) * 64 + col);
#pragma unroll
            for (int j = 0; j < 8; ++j) Vtl[col + j][row] = vv[j];
        }
#pragma unroll
        for (int p = 0; p < 4; ++p) {
            const int row = p * 32 + (tid >> 3);
            const int col = (tid & 7) * 8;
            const int e   = E0 + row;
            bf16x8 ev;
#pragma unroll
            for (int j = 0; j < 8; ++j) ev[j] = (bf16_t)0.0f;
            if (e < 1024) ev = load8(Er + (size_t)e * 64 + col);
            *(bf16x8*)&Erl[row][col] = ev;
        }
        __syncthreads();

        // --- QK^T and G strip via MFMA ---
        f32x4 sacc[4], gacc[5];
#pragma unroll
        for (int nt = 0; nt < 4; ++nt)
#pragma unroll
            for (int r = 0; r < 4; ++r) sacc[nt][r] = 0.0f;
#pragma unroll
        for (int gt = 0; gt < 5; ++gt)
#pragma unroll
            for (int r = 0; r < 4; ++r) gacc[gt][r] = 0.0f;

#pragma unroll
        for (int kk = 0; kk < 2; ++kk) {
#pragma unroll
            for (int nt = 0; nt < 4; ++nt) {
                bf16x8 bk_ = *(const bf16x8*)&Kl[nt * 16 + l16][kk * 32 + quad * 8];
                sacc[nt] = MFMA16(aq[kk], bk_, sacc[nt]);
            }
#pragma unroll
            for (int gt = 0; gt < 5; ++gt) {
                bf16x8 be = *(const bf16x8*)&Erl[u0 + gt * 16 + l16][kk * 32 + quad * 8];
                gacc[gt] = MFMA16(aq[kk], be, gacc[gt]);
            }
        }
        // park G in wave-private LDS (intra-wave DS ordering guarantees RAW)
#pragma unroll
        for (int gt = 0; gt < 5; ++gt)
#pragma unroll
            for (int r = 0; r < 4; ++r)
                Gl[w][quad * 4 + r][gt * 16 + l16] = (bf16_t)gacc[gt][r];

        // --- logits + causal mask ---
#pragma unroll
        for (int nt = 0; nt < 4; ++nt) {
            const int t_idx = t0 + nt * 16 + l16;
#pragma unroll
            for (int r = 0; r < 4; ++r) {
                const int i     = quad * 4 + r;
                const int s_idx = s0w + i;
                float sv = (sacc[nt][r] + (float)Gl[w][i][15 - i + nt * 16 + l16]) * 0.125f;
                if (t_idx > s_idx) sv = -1e9f;
                sacc[nt][r] = sv;
            }
        }

        // --- online softmax (rows quad-local; xor over lane bits 0..3) ---
        float alpha[4];
#pragma unroll
        for (int r = 0; r < 4; ++r) {
            float vm = fmaxf(fmaxf(sacc[0][r], sacc[1][r]), fmaxf(sacc[2][r], sacc[3][r]));
#pragma unroll
            for (int off = 1; off < 16; off <<= 1)
                vm = fmaxf(vm, __shfl_xor(vm, off));
            const float mnew = fmaxf(mrow[r], vm);
            alpha[r] = __builtin_exp2f((mrow[r] - mnew) * LOG2E);
            mrow[r]  = mnew;
            float rs = 0.0f;
#pragma unroll
            for (int nt = 0; nt < 4; ++nt) {
                const float p_ = __builtin_exp2f((sacc[nt][r] - mnew) * LOG2E);
                sacc[nt][r] = p_;
                rs += p_;
            }
#pragma unroll
            for (int off = 1; off < 16; off <<= 1)
                rs += __shfl_xor(rs, off);
            lrow[r] = lrow[r] * alpha[r] + rs;
            o[0][r] *= alpha[r]; o[1][r] *= alpha[r];
            o[2][r] *= alpha[r]; o[3][r] *= alpha[r];
        }

        // --- P to wave-private LDS (bf16), then PV via MFMA ---
#pragma unroll
        for (int nt = 0; nt < 4; ++nt)
#pragma unroll
            for (int r = 0; r < 4; ++r)
                Pl[w][quad * 4 + r][nt * 16 + l16] = (bf16_t)sacc[nt][r];

#pragma unroll
        for (int kk = 0; kk < 2; ++kk) {
            bf16x8 ap = *(const bf16x8*)&Pl[w][l16][kk * 32 + quad * 8];
#pragma unroll
            for (int nt = 0; nt < 4; ++nt) {
                bf16x8 bv_ = *(const bf16x8*)&Vtl[nt * 16 + l16][kk * 32 + quad * 8];
                o[nt] = MFMA16(ap, bv_, o[nt]);
            }
        }
    }

    // --- epilogue: att[b, s, h*64+d] = o / l ---
#pragma unroll
    for (int nt = 0; nt < 4; ++nt) {
#pragma unroll
        for (int r = 0; r < 4; ++r) {
            const int s_idx = s0w + quad * 4 + r;
            const int d     = nt * 16 + l16;
            const float v   = o[nt][r] / lrow[r];
            att[((size_t)b * 1024 + s_idx) * 768 + h * 64 + d] = (bf16_t)v;
        }
    }
}

// ---------------------------------------------------------------------------
extern "C" void kernel_launch(void* const* d_in, const int* in_sizes, int n_in,
                              void* d_out, int out_size, void* d_ws, size_t ws_size,
                              hipStream_t stream)
{
    const float* Q  = (const float*)d_in[0];
    const float* K  = (const float*)d_in[1];
    const float* V  = (const float*)d_in[2];
    // d_in[3] = causal mask — semantics reproduced in-kernel
    const float* Wq = (const float*)d_in[4];
    const float* bq = (const float*)d_in[5];
    const float* Wk = (const float*)d_in[6];
    const float* bk = (const float*)d_in[7];
    const float* Wv = (const float*)d_in[8];
    const float* bv = (const float*)d_in[9];
    const float* Wo = (const float*)d_in[10];
    const float* bo = (const float*)d_in[11];
    const float* Er = (const float*)d_in[12];
    float* out      = (float*)d_out;     // fp32 output (reference dtype)

    const size_t per = (size_t)8 * 12 * 1024 * 64;
    // q (bf16, 12.6MB) borrows d_out's front half (25.2MB fp32); q is dead
    // before the final fp32 epilogue overwrites the buffer.
    bf16_t* qbuf = (bf16_t*)d_out;
    bf16_t* kbuf = (bf16_t*)d_ws;
    bf16_t* vbuf = kbuf + per;
    bf16_t* abuf = vbuf + per;           // (B,S,768) attention out, bf16

    dim3 gp(128, 12), bp(256);
    proj_gemm<float, bf16_t><<<gp, bp, 0, stream>>>(Q, Wq, bq, qbuf, 0);
    proj_gemm<float, bf16_t><<<gp, bp, 0, stream>>>(K, Wk, bk, kbuf, 0);
    proj_gemm<float, bf16_t><<<gp, bp, 0, stream>>>(V, Wv, bv, vbuf, 0);
    attn_kernel<<<dim3(8 * 12 * 16), bp, 0, stream>>>(qbuf, kbuf, vbuf, Er, abuf);
    proj_gemm<bf16_t, float><<<gp, bp, 0, stream>>>(abuf, Wo, bo, out, 1);
}

// Round 7
// 442.338 us; speedup vs baseline: 4.7256x; 1.0392x over previous
//
#include <hip/hip_runtime.h>

typedef __bf16 bf16_t;
typedef __bf16 bf16x8 __attribute__((ext_vector_type(8)));
typedef float  f32x4  __attribute__((ext_vector_type(4)));

#define MFMA16(a, b, c) __builtin_amdgcn_mfma_f32_16x16x32_bf16((a), (b), (c), 0, 0, 0)
#define LOG2E 1.44269504f

// 8-element loaders -> bf16x8 (fp32 source converts on the fly)
__device__ inline bf16x8 load8(const bf16_t* p) { return *(const bf16x8*)p; }
__device__ inline bf16x8 load8(const float* p) {
    f32x4 a = *(const f32x4*)p;
    f32x4 b = *(const f32x4*)(p + 4);
    bf16x8 r;
    r[0] = (bf16_t)a[0]; r[1] = (bf16_t)a[1]; r[2] = (bf16_t)a[2]; r[3] = (bf16_t)a[3];
    r[4] = (bf16_t)b[0]; r[5] = (bf16_t)b[1]; r[6] = (bf16_t)b[2]; r[7] = (bf16_t)b[3];
    return r;
}

// ---------------------------------------------------------------------------
// cvt_er: Er fp32 (1024x64) -> bf16 (1152x64), tail 128 rows zero-filled so
// the attention staging needs no bounds checks.
// ---------------------------------------------------------------------------
__global__ void cvt_er(const float* __restrict__ Er, bf16_t* __restrict__ Erb)
{
    const int idx = blockIdx.x * 256 + threadIdx.x;   // grid 288 -> 73728
    Erb[idx] = (idx < 65536) ? (bf16_t)Er[idx] : (bf16_t)0.0f;
}

// ---------------------------------------------------------------------------
// gemm_tile: C[m,n] = X[m,:] . W[n,:] + bias[n]   (X @ W^T + b)
// 64x64 tile, 4 waves, 16x64 slab each (ref-checked m92/m97 pattern).
// mode 0: (B,H,S,64) head-major; mode 1: flat [m*768+n];
// mode 2: (B,H,64,S) head-major TRANSPOSED (for V -> PV needs V^T).
// ---------------------------------------------------------------------------
template <typename XT, typename OT>
__device__ __forceinline__ void
gemm_tile(const XT* __restrict__ X, const float* __restrict__ W,
          const float* __restrict__ bias, OT* __restrict__ Out, int mode,
          int m0, int n0, bf16_t (*Al)[72], bf16_t (*Bl)[72])
{
    const int tid  = threadIdx.x;
    const int w    = tid >> 6;
    const int lane = tid & 63;
    const int quad = lane >> 4;
    const int l16  = lane & 15;

    f32x4 acc[4];
#pragma unroll
    for (int nt = 0; nt < 4; ++nt)
#pragma unroll
        for (int r = 0; r < 4; ++r) acc[nt][r] = 0.0f;

    for (int kc = 0; kc < 12; ++kc) {
        const int k0 = kc * 64;
        __syncthreads();
#pragma unroll
        for (int p = 0; p < 2; ++p) {
            const int row = p * 32 + (tid >> 3);
            const int col = (tid & 7) * 8;
            *(bf16x8*)&Al[row][col] = load8(X + (size_t)(m0 + row) * 768 + k0 + col);
            *(bf16x8*)&Bl[row][col] = load8(W + (size_t)(n0 + row) * 768 + k0 + col);
        }
        __syncthreads();
#pragma unroll
        for (int kk = 0; kk < 2; ++kk) {
            bf16x8 a = *(const bf16x8*)&Al[16 * w + l16][kk * 32 + quad * 8];
#pragma unroll
            for (int nt = 0; nt < 4; ++nt) {
                bf16x8 b = *(const bf16x8*)&Bl[16 * nt + l16][kk * 32 + quad * 8];
                acc[nt] = MFMA16(a, b, acc[nt]);
            }
        }
    }

#pragma unroll
    for (int nt = 0; nt < 4; ++nt) {
        const int n  = n0 + nt * 16 + l16;
        const float bn = bias[n];
#pragma unroll
        for (int r = 0; r < 4; ++r) {
            const int m = m0 + 16 * w + quad * 4 + r;
            const float v = acc[nt][r] + bn;
            if (mode == 0) {
                const int bb = m >> 10, ss = m & 1023, hh = n >> 6, dd = n & 63;
                Out[(((size_t)(bb * 12 + hh)) * 1024 + ss) * 64 + dd] = (OT)v;
            } else if (mode == 2) {
                const int bb = m >> 10, ss = m & 1023, hh = n >> 6, dd = n & 63;
                Out[(((size_t)(bb * 12 + hh)) * 64 + dd) * 1024 + ss] = (OT)v;
            } else {
                Out[(size_t)m * 768 + n] = (OT)v;
            }
        }
    }
}

__global__ void __launch_bounds__(256)
qkv_proj(const float* __restrict__ Q, const float* __restrict__ K,
         const float* __restrict__ V,
         const float* __restrict__ Wq, const float* __restrict__ Wk,
         const float* __restrict__ Wv,
         const float* __restrict__ bq, const float* __restrict__ bk,
         const float* __restrict__ bv,
         bf16_t* __restrict__ qo, bf16_t* __restrict__ ko, bf16_t* __restrict__ vo)
{
    __shared__ bf16_t Al[64][72];
    __shared__ bf16_t Bl[64][72];
    const int z = blockIdx.z;
    const float* X  = (z == 0) ? Q  : (z == 1) ? K  : V;
    const float* W  = (z == 0) ? Wq : (z == 1) ? Wk : Wv;
    const float* bs = (z == 0) ? bq : (z == 1) ? bk : bv;
    bf16_t* Out     = (z == 0) ? qo : (z == 1) ? ko : vo;
    gemm_tile<float, bf16_t>(X, W, bs, Out, (z == 2) ? 2 : 0,
                             blockIdx.x * 64, blockIdx.y * 64, Al, Bl);
}

__global__ void __launch_bounds__(256)
out_proj(const bf16_t* __restrict__ X, const float* __restrict__ W,
         const float* __restrict__ bias, float* __restrict__ Out)
{
    __shared__ bf16_t Al[64][72];
    __shared__ bf16_t Bl[64][72];
    gemm_tile<bf16_t, float>(X, W, bias, Out, 1,
                             blockIdx.x * 64, blockIdx.y * 64, Al, Bl);
}

// ---------------------------------------------------------------------------
// attn_kernel: MFMA flash attention with Music-Transformer relative position.
// Block = (b, h, 64 q-rows). 4 waves x 16 q-rows.
// Srel[s,t] = q[s].Er[1023-s+t]; strip GEMM G[i,u]=q.Er[E0+u0+u], then the
// skew Srel[i][j]=G[i][15-i+j] is a quad-local lane rotation (bpermute) —
// same quad, same acc register, shifted lane.
// V is pre-transposed (B,H,64,S); Er pre-converted bf16 + zero tail.
// Er window ring-buffers (shift +64/iter); next tile prefetched to registers.
// ---------------------------------------------------------------------------
__global__ void __launch_bounds__(256)
attn_kernel(const bf16_t* __restrict__ qb, const bf16_t* __restrict__ kb,
            const bf16_t* __restrict__ vt, const bf16_t* __restrict__ Erb,
            bf16_t* __restrict__ att)
{
    __shared__ bf16_t Kl[64][72];        // K tile, row t_local
    __shared__ bf16_t Vtl[64][72];       // V^T tile: [d][t_local] (direct stage)
    __shared__ bf16_t Erl[128][72];      // Er ring: phys row = e & 127
    __shared__ bf16_t Pl[4][16][72];     // per-wave P round-trip (wave-private)

    const int tid  = threadIdx.x;
    const int bid  = blockIdx.x;
    const int qt   = 15 - (bid & 15);    // heavy q-tiles dispatched first
    const int bh   = bid >> 4;           // 0..95
    const int b    = bh / 12;
    const int h    = bh % 12;
    const int s0   = qt * 64;
    const int w    = tid >> 6;
    const int lane = tid & 63;
    const int quad = lane >> 4;
    const int l16  = lane & 15;
    const int s0w  = s0 + 16 * w;
    const int u0   = 48 - 16 * w;

    const bf16_t* qp = qb + (size_t)bh * 65536;
    const bf16_t* kp = kb + (size_t)bh * 65536;
    const bf16_t* vp = vt + (size_t)bh * 65536;   // (64 d) x (1024 t)

    const int srow = tid >> 3;          // 0..31
    const int scol = (tid & 7) * 8;     // 0..56

    // q fragments (A-layout: [m=l16][k=quad*8+j])
    bf16x8 aq[2];
#pragma unroll
    for (int kk = 0; kk < 2; ++kk)
        aq[kk] = load8(qp + (size_t)(s0w + l16) * 64 + kk * 32 + quad * 8);

    // --- initial stage: tile 0 + full 128-row Er window ---
    const int E00 = 960 - s0;
#pragma unroll
    for (int p = 0; p < 2; ++p) {
        *(bf16x8*)&Kl[p * 32 + srow][scol]  = load8(kp + (size_t)(p * 32 + srow) * 64 + scol);
        *(bf16x8*)&Vtl[p * 32 + srow][scol] = load8(vp + (size_t)(p * 32 + srow) * 1024 + scol);
    }
#pragma unroll
    for (int p = 0; p < 4; ++p) {
        const int e = E00 + p * 32 + srow;
        *(bf16x8*)&Erl[e & 127][scol] = load8(Erb + (size_t)e * 64 + scol);
    }
    __syncthreads();

    float mrow[4], lrow[4];
    f32x4 o[4];
#pragma unroll
    for (int r = 0; r < 4; ++r) { mrow[r] = -1e30f; lrow[r] = 0.0f; }
#pragma unroll
    for (int nt = 0; nt < 4; ++nt)
#pragma unroll
        for (int r = 0; r < 4; ++r) o[nt][r] = 0.0f;

    const int nT = qt + 1;
    for (int tt = 0; tt < nT; ++tt) {
        const int t0 = tt * 64;
        const int E0 = E00 + t0;
        const bool more = (tt + 1 < nT);

        // --- prefetch next tile into registers (in flight during compute) ---
        bf16x8 kpre[2], vpre[2], epre[2];
        if (more) {
            const int t0n = t0 + 64;
#pragma unroll
            for (int p = 0; p < 2; ++p) {
                kpre[p] = load8(kp + (size_t)(t0n + p * 32 + srow) * 64 + scol);
                vpre[p] = load8(vp + (size_t)(p * 32 + srow) * 1024 + t0n + scol);
                const int e = E0 + 128 + p * 32 + srow;     // new 64 rows of window
                epre[p] = load8(Erb + (size_t)e * 64 + scol);
            }
        }

        // --- QK^T and G strip via MFMA ---
        f32x4 sacc[4], gacc[5];
#pragma unroll
        for (int nt = 0; nt < 4; ++nt)
#pragma unroll
            for (int r = 0; r < 4; ++r) sacc[nt][r] = 0.0f;
#pragma unroll
        for (int gt = 0; gt < 5; ++gt)
#pragma unroll
            for (int r = 0; r < 4; ++r) gacc[gt][r] = 0.0f;

#pragma unroll
        for (int kk = 0; kk < 2; ++kk) {
#pragma unroll
            for (int nt = 0; nt < 4; ++nt) {
                if (t0 + nt * 16 <= s0w + 15) {   // wave-uniform: skip fully-masked tiles
                    bf16x8 bk_ = *(const bf16x8*)&Kl[nt * 16 + l16][kk * 32 + quad * 8];
                    sacc[nt] = MFMA16(aq[kk], bk_, sacc[nt]);
                }
            }
#pragma unroll
            for (int gt = 0; gt < 5; ++gt) {
                const int er = (E0 + u0 + gt * 16 + l16) & 127;
                bf16x8 be = *(const bf16x8*)&Erl[er][kk * 32 + quad * 8];
                gacc[gt] = MFMA16(aq[kk], be, gacc[gt]);
            }
        }

        // --- skew via quad-local rotation + logits + causal mask ---
        // Srel row i=quad*4+r needs G[i][15-i+j]: same quad, same reg r,
        // lane (l16 + 15-i)&15; tile nt if l16<=i else nt+1.
#pragma unroll
        for (int r = 0; r < 4; ++r) {
            const int i   = quad * 4 + r;
            const int cc  = 15 - i + l16;              // 0..30
            const int src = (lane & 48) | (cc & 15);
            const bool lo = (cc < 16);
            float rot[5];
#pragma unroll
            for (int gt = 0; gt < 5; ++gt) rot[gt] = __shfl(gacc[gt][r], src);
#pragma unroll
            for (int nt = 0; nt < 4; ++nt) {
                const float g = lo ? rot[nt] : rot[nt + 1];
                float sv = (sacc[nt][r] + g) * 0.125f;
                if (t0 + nt * 16 + l16 > s0w + i) sv = -1e9f;
                sacc[nt][r] = sv;
            }
        }

        // --- online softmax (rows quad-local; xor over lane bits 0..3) ---
#pragma unroll
        for (int r = 0; r < 4; ++r) {
            float vm = fmaxf(fmaxf(sacc[0][r], sacc[1][r]), fmaxf(sacc[2][r], sacc[3][r]));
#pragma unroll
            for (int off = 1; off < 16; off <<= 1)
                vm = fmaxf(vm, __shfl_xor(vm, off));
            const float mnew  = fmaxf(mrow[r], vm);
            const float alpha = __builtin_exp2f((mrow[r] - mnew) * LOG2E);
            mrow[r] = mnew;
            float rs = 0.0f;
#pragma unroll
            for (int nt = 0; nt < 4; ++nt) {
                const float p_ = __builtin_exp2f((sacc[nt][r] - mnew) * LOG2E);
                sacc[nt][r] = p_;
                rs += p_;
            }
#pragma unroll
            for (int off = 1; off < 16; off <<= 1)
                rs += __shfl_xor(rs, off);
            lrow[r] = lrow[r] * alpha + rs;
            o[0][r] *= alpha; o[1][r] *= alpha;
            o[2][r] *= alpha; o[3][r] *= alpha;
        }

        // --- P to wave-private LDS (C/D -> A transpose), then PV ---
#pragma unroll
        for (int nt = 0; nt < 4; ++nt)
#pragma unroll
            for (int r = 0; r < 4; ++r)
                Pl[w][quad * 4 + r][nt * 16 + l16] = (bf16_t)sacc[nt][r];

#pragma unroll
        for (int kk = 0; kk < 2; ++kk) {
            bf16x8 ap = *(const bf16x8*)&Pl[w][l16][kk * 32 + quad * 8];
#pragma unroll
            for (int nt = 0; nt < 4; ++nt) {
                bf16x8 bv_ = *(const bf16x8*)&Vtl[nt * 16 + l16][kk * 32 + quad * 8];
                o[nt] = MFMA16(ap, bv_, o[nt]);
            }
        }

        // --- commit prefetched tile to LDS ---
        if (more) {
            __syncthreads();
#pragma unroll
            for (int p = 0; p < 2; ++p) {
                *(bf16x8*)&Kl[p * 32 + srow][scol]  = kpre[p];
                *(bf16x8*)&Vtl[p * 32 + srow][scol] = vpre[p];
                const int e = E0 + p * 32 + srow;   // (E0+128+ro)&127 == (E0+ro)&127
                *(bf16x8*)&Erl[e & 127][scol] = epre[p];
            }
            __syncthreads();
        }
    }

    // --- epilogue: att[b, s, h*64+d] = o / l ---
#pragma unroll
    for (int nt = 0; nt < 4; ++nt) {
#pragma unroll
        for (int r = 0; r < 4; ++r) {
            const int s_idx = s0w + quad * 4 + r;
            const int d     = nt * 16 + l16;
            att[((size_t)b * 1024 + s_idx) * 768 + h * 64 + d] = (bf16_t)(o[nt][r] / lrow[r]);
        }
    }
}

// ---------------------------------------------------------------------------
extern "C" void kernel_launch(void* const* d_in, const int* in_sizes, int n_in,
                              void* d_out, int out_size, void* d_ws, size_t ws_size,
                              hipStream_t stream)
{
    const float* Q  = (const float*)d_in[0];
    const float* K  = (const float*)d_in[1];
    const float* V  = (const float*)d_in[2];
    // d_in[3] = causal mask — semantics reproduced in-kernel
    const float* Wq = (const float*)d_in[4];
    const float* bq = (const float*)d_in[5];
    const float* Wk = (const float*)d_in[6];
    const float* bk = (const float*)d_in[7];
    const float* Wv = (const float*)d_in[8];
    const float* bv = (const float*)d_in[9];
    const float* Wo = (const float*)d_in[10];
    const float* bo = (const float*)d_in[11];
    const float* Er = (const float*)d_in[12];
    float* out      = (float*)d_out;     // fp32 output (reference dtype)

    const size_t per = (size_t)8 * 12 * 1024 * 64;   // 6.29M elems
    // d_out (25.2MB fp32) front: qbuf (bf16, 12.6MB) + Erb (144KB) — both dead
    // before the fp32 out_proj epilogue overwrites d_out.
    bf16_t* qbuf  = (bf16_t*)d_out;
    bf16_t* Erb   = qbuf + per;          // 1152 x 64 bf16, zero tail
    bf16_t* kbuf  = (bf16_t*)d_ws;
    bf16_t* vtbuf = kbuf + per;          // (B,H,64,S) V^T
    bf16_t* abuf  = vtbuf + per;         // (B,S,768) attention out, bf16

    cvt_er<<<dim3(288), dim3(256), 0, stream>>>(Er, Erb);
    qkv_proj<<<dim3(128, 12, 3), dim3(256), 0, stream>>>(Q, K, V, Wq, Wk, Wv,
                                                         bq, bk, bv, qbuf, kbuf, vtbuf);
    attn_kernel<<<dim3(1536), dim3(256), 0, stream>>>(qbuf, kbuf, vtbuf, Erb, abuf);
    out_proj<<<dim3(128, 12), dim3(256), 0, stream>>>(abuf, Wo, bo, out);
}